// Round 10
// baseline (258.066 us; speedup 1.0000x reference)
//
#include <hip/hip_runtime.h>
#include <hip/hip_bf16.h>
#include <math.h>

#define Bv 8
#define Tv 32
#define Nv 500
#define NP 512           /* padded node dim for the AGG GEMM */
#define Fin 64
#define Hv 128
#define Ev 8000
#define Kv 3
#define BT (Bv*Tv)       /* 256 */
#define NCOL (BT*Fin)    /* 16384: X2b/AGG2 row length */
#define TP (Tv+2)        /* 34 LDS time rows (1 pad each side) */
#define KK (Kv*Hv)       /* 384 */
#define LDSROW 144       /* 288B row stride */

typedef __attribute__((ext_vector_type(8))) short s8v;   // 8 bf16
typedef __attribute__((ext_vector_type(4))) float f4v;   // MFMA acc

// branch-free erf (A&S 7.1.26, |err| <= 1.5e-7)
__device__ __forceinline__ float gelu_exact(float v){
    float t  = v*0.70710678118654752440f;
    float ax = fabsf(t);
    float k  = __builtin_amdgcn_rcpf(fmaf(0.3275911f, ax, 1.0f));
    float p  = k*fmaf(k, fmaf(k, fmaf(k, fmaf(k, 1.061405429f, -1.453152027f),
                                      1.421413741f), -0.284496736f), 0.254829592f);
    float e  = __expf(-ax*ax);
    float er = fmaf(-p, e, 1.0f);
    er = copysignf(er, t);
    return 0.5f*v*(1.0f + er);
}
__device__ __forceinline__ short f2bs(float f){
    union { __hip_bfloat16 h; short s; } u;
    u.h = __float2bfloat16(f);
    return u.s;
}

// ---- k_prep (ONE kernel, 2336 blocks):
//  [0,2047]    LDS-tiled transpose x(bt,n,c) -> XT(bt*64+c, n-pad512) bf16
//              AND X2b(n, bt*64+c) bf16 (straight from pre-transpose regs)
//  [2048,2079] A-builder: block i owns A rows [i*16, i*16+16). Scans the
//              96KB L2-hot edge list twice (deg -> dinv; then own-row
//              accumulate into zeroed LDS fp32 rows + self-loop diag),
//              writes bf16 rows of Ab directly. Replaces the former
//              zero-Af32 + k_scat + k_cvt chain (2 kernels + 1MB traffic).
//  [2080,2335] weight repacks.
__global__ __launch_bounds__(256) void k_prep(const float* __restrict__ x,
        short* __restrict__ XT, short* __restrict__ X2b, short* __restrict__ Ab,
        const float* __restrict__ W, const float* __restrict__ Wg,
        const float* __restrict__ Wr,
        short* __restrict__ W2, short* __restrict__ Wgt, short* __restrict__ Wrt,
        const int* __restrict__ ei, const float* __restrict__ ew){
    int bid = blockIdx.x;
    int tid = threadIdx.x;
    if (bid < 2048){
        // one 64(n) x 64(c) tile of batch-row bt
        __shared__ short t[64][72];          // +8 pad
        int bt = bid >> 3;
        int n0 = (bid & 7) * 64;
        int r   = tid >> 2;                  // tile n-row 0..63
        int c16 = (tid & 3) * 16;            // c chunk base
        int n = n0 + r;
        short sv[16];
        if (n < Nv){
            const float4* src = (const float4*)(x + ((size_t)bt*Nv + n)*64 + c16);
            #pragma unroll
            for (int j = 0; j < 4; ++j){
                float4 v = src[j];
                sv[j*4+0]=f2bs(v.x); sv[j*4+1]=f2bs(v.y);
                sv[j*4+2]=f2bs(v.z); sv[j*4+3]=f2bs(v.w);
            }
            // identity-layout bf16 copy for mega (32B, 128B segments per 4 lanes)
            short* xb = X2b + (size_t)n*NCOL + bt*64 + c16;
            *(s8v*)xb       = *(s8v*)&sv[0];
            *(s8v*)(xb + 8) = *(s8v*)&sv[8];
        } else {
            #pragma unroll
            for (int j = 0; j < 16; ++j) sv[j] = 0;
        }
        #pragma unroll
        for (int j = 0; j < 16; ++j) t[r][c16+j] = sv[j];
        __syncthreads();
        int cc  = tid >> 2;                  // c 0..63
        int nn0 = (tid & 3) * 16;
        short ov[16];
        #pragma unroll
        for (int j = 0; j < 16; ++j) ov[j] = t[nn0+j][cc];
        short* dst = XT + (size_t)(bt*64 + cc)*NP + n0 + nn0;
        *(s8v*)dst       = *(s8v*)&ov[0];
        *(s8v*)(dst + 8) = *(s8v*)&ov[8];
    } else if (bid < 2080){
        // ---- A-builder for rows [r0, r0+16) ----
        __shared__ float deg[Nv];            // becomes dinv in place
        __shared__ float rowbuf[16*NP];      // 32KB, zero-init = A's zeros
        int r0 = (bid - 2048)*16;
        for (int i = tid; i < Nv; i += 256) deg[i] = 1.0f;   // self-loop weight
        for (int i = tid; i < 16*NP; i += 256) rowbuf[i] = 0.f;
        __syncthreads();
        for (int e = tid; e < Ev; e += 256)
            atomicAdd(&deg[ei[Ev + e]], ew[e]);
        __syncthreads();
        for (int i = tid; i < Nv; i += 256){
            float d = deg[i];
            deg[i] = (d > 0.f) ? rsqrtf(d) : 0.f;            // now dinv
        }
        __syncthreads();
        for (int e = tid; e < Ev; e += 256){
            int d = ei[Ev + e];
            unsigned g = (unsigned)(d - r0);
            if (g < 16u){
                int s = ei[e];
                atomicAdd(&rowbuf[g*NP + s], deg[s]*ew[e]*deg[d]);
            }
        }
        __syncthreads();
        if (tid < 16){                       // self-loop diagonal
            int row = r0 + tid;
            if (row < Nv){
                float dv = deg[row];
                rowbuf[tid*NP + row] += dv*dv;
            }
        }
        __syncthreads();
        for (int i = tid; i < 16*NP/8; i += 256){            // 1024 s8v groups
            const float* rp = &rowbuf[i*8];
            s8v o;
            #pragma unroll
            for (int j = 0; j < 8; ++j) o[j] = f2bs(rp[j]);
            *(s8v*)(Ab + (size_t)r0*NP + i*8) = o;
        }
    } else {
        int idx = (bid - 2080)*256 + tid;
        if (idx < Hv*Hv*Kv){
            int o = idx/(Hv*Kv);
            int rem = idx - o*(Hv*Kv);
            int i = rem/Kv, k = rem - i*Kv;
            W2[o*KK + k*Hv + i] = f2bs(W[idx]);
        } else if (idx < Hv*Hv*Kv + Hv*64){
            int j = idx - Hv*Hv*Kv;
            int o = j >> 6, k = j & 63;
            Wgt[j] = f2bs(Wg[k*Hv + o]);
        } else if (idx < Hv*Hv*Kv + 2*Hv*64){
            int j = idx - Hv*Hv*Kv - Hv*64;
            int o = j >> 6, k = j & 63;
            Wrt[j] = f2bs(Wr[k*Hv + o]);
        }
    }
}

// ---- k_gemm (verified R8): AGG2[n][col] = sum_k Ab[n][k] * XT[col][k]
//      M=512, N=16384, K=512. grid 512 = 4 i-tiles x 128 j-tiles. ----
__global__ __launch_bounds__(256) void k_gemm(const short* __restrict__ Ab,
        const short* __restrict__ XT, short* __restrict__ AGG2){
    int tid  = threadIdx.x;
    int w    = tid >> 6;
    int lane = tid & 63;
    int quad = lane >> 4;
    int laneo = lane & 15;
    int bid = blockIdx.x;
    int jt = bid & 127, it = bid >> 7;
    int i0 = it*128;
    int j0 = jt*128 + w*32;

    f4v acc[8][2];
    #pragma unroll
    for (int m = 0; m < 8; ++m){
        acc[m][0] = (f4v){0.f,0.f,0.f,0.f};
        acc[m][1] = (f4v){0.f,0.f,0.f,0.f};
    }
    #pragma unroll 2
    for (int ks = 0; ks < 16; ++ks){
        int k0 = ks*32 + quad*8;
        s8v bfr[2];
        #pragma unroll
        for (int nt = 0; nt < 2; ++nt)
            bfr[nt] = *(const s8v*)(XT + (size_t)(j0 + nt*16 + laneo)*NP + k0);
        #pragma unroll
        for (int m = 0; m < 8; ++m){
            s8v afr = *(const s8v*)(Ab + (size_t)(i0 + m*16 + laneo)*NP + k0);
            acc[m][0] = __builtin_amdgcn_mfma_f32_16x16x32_bf16(afr, bfr[0], acc[m][0], 0,0,0);
            acc[m][1] = __builtin_amdgcn_mfma_f32_16x16x32_bf16(afr, bfr[1], acc[m][1], 0,0,0);
        }
    }
    #pragma unroll
    for (int m = 0; m < 8; ++m){
        #pragma unroll
        for (int r = 0; r < 4; ++r){
            int row = i0 + m*16 + quad*4 + r;
            if (row < Nv){
                #pragma unroll
                for (int nt = 0; nt < 2; ++nt)
                    AGG2[(size_t)row*NCOL + j0 + nt*16 + laneo] = f2bs(acc[m][nt][r]);
            }
        }
    }
}

// ---- mega kernel: R8 structure (63.7us verified) with launch_bounds(256,3).
//      Natural VGPR 116-124 <= 170 budget at 3 waves/EU -> no spill expected
//      (R7 precedent). If FETCH_SIZE balloons past ~40MB, revert to (256,2). ----
__global__ __launch_bounds__(256, 3) void k_mega(
        const short* __restrict__ AGG2, const short* __restrict__ X2b,
        const short* __restrict__ W2, const short* __restrict__ Wgt,
        const short* __restrict__ Wrt,
        const float* __restrict__ bg, const float* __restrict__ btm,
        const float* __restrict__ br, const float* __restrict__ lw,
        const float* __restrict__ lb, float* __restrict__ out){
    __shared__ short hs[4*TP*LDSROW];      // 39168 B
    __shared__ float red[Tv][4][2];
    int tid  = threadIdx.x;
    int w    = tid >> 6;
    int lane = tid & 63;
    int quad = lane >> 4;
    int laneo = lane & 15;
    int bid = blockIdx.x;
    int b  = bid / 125;
    int n0 = (bid - b*125) * 4;
    int o_base = w*32;

    float bgv[2], bbv[2], brv[2], lwv[2], lbv[2];
    #pragma unroll
    for (int nt = 0; nt < 2; ++nt){
        int o = o_base + nt*16 + laneo;
        bgv[nt] = bg[o]; bbv[nt] = btm[o]; brv[nt] = br[o];
        lwv[nt] = lw[o]; lbv[nt] = lb[o];
    }

    s8v bwg[2][2];
    #pragma unroll
    for (int nt = 0; nt < 2; ++nt){
        const short* wp = Wgt + (o_base + nt*16 + laneo)*64 + quad*8;
        bwg[nt][0] = *(const s8v*)wp;
        bwg[nt][1] = *(const s8v*)(wp + 32);
    }

    if (tid < 128){
        int node = tid >> 5, rem = tid & 31;
        int tp = (rem >> 4)*(TP-1), c8 = rem & 15;
        s8v z = {0,0,0,0,0,0,0,0};
        *(s8v*)&hs[node*(TP*LDSROW) + tp*LDSROW + c8*8] = z;
    }

    for (int g = 0; g < 4; ++g){
        int n = n0 + g;
        const short* ap = AGG2 + ((size_t)n*BT + b*Tv)*64;
        #pragma unroll
        for (int m = 0; m < 2; ++m){
            const short* arp = ap + (m*16 + laneo)*64 + quad*8;
            s8v a0 = *(const s8v*)arp;
            s8v a1 = *(const s8v*)(arp + 32);
            f4v h0 = {0.f,0.f,0.f,0.f}, h1 = {0.f,0.f,0.f,0.f};
            h0 = __builtin_amdgcn_mfma_f32_16x16x32_bf16(a0, bwg[0][0], h0, 0,0,0);
            h0 = __builtin_amdgcn_mfma_f32_16x16x32_bf16(a1, bwg[0][1], h0, 0,0,0);
            h1 = __builtin_amdgcn_mfma_f32_16x16x32_bf16(a0, bwg[1][0], h1, 0,0,0);
            h1 = __builtin_amdgcn_mfma_f32_16x16x32_bf16(a1, bwg[1][1], h1, 0,0,0);
            #pragma unroll
            for (int r = 0; r < 4; ++r){
                int tp = m*16 + quad*4 + r + 1;
                short* hrow = &hs[g*(TP*LDSROW) + tp*LDSROW];
                hrow[o_base + laneo]      = f2bs(gelu_exact(h0[r] + bgv[0]));
                hrow[o_base + 16 + laneo] = f2bs(gelu_exact(h1[r] + bgv[1]));
            }
        }
    }

    s8v breg[2][12], bwr[2][2];
    #pragma unroll
    for (int nt = 0; nt < 2; ++nt){
        int o = o_base + nt*16 + laneo;
        const short* wp = W2 + o*KK + quad*8;
        #pragma unroll
        for (int s = 0; s < 12; ++s)
            breg[nt][s] = *(const s8v*)(wp + s*32);
        const short* wr = Wrt + o*64 + quad*8;
        bwr[nt][0] = *(const s8v*)wr;
        bwr[nt][1] = *(const s8v*)(wr + 32);
    }
    __syncthreads();

    for (int g = 0; g < 4; ++g){
        int n = n0 + g;
        f4v acc[2][2];
        #pragma unroll
        for (int m = 0; m < 2; ++m)
            #pragma unroll
            for (int nt = 0; nt < 2; ++nt)
                acc[m][nt] = (f4v){0.f,0.f,0.f,0.f};
        #pragma unroll
        for (int m = 0; m < 2; ++m){
            #pragma unroll
            for (int s = 0; s < 12; ++s){
                int k  = s >> 2;
                int i0 = (s & 3) * 32;
                int tp = m*16 + laneo + k;
                s8v a = *(const s8v*)&hs[g*(TP*LDSROW) + tp*LDSROW + i0 + quad*8];
                acc[m][0] = __builtin_amdgcn_mfma_f32_16x16x32_bf16(a, breg[0][s], acc[m][0], 0,0,0);
                acc[m][1] = __builtin_amdgcn_mfma_f32_16x16x32_bf16(a, breg[1][s], acc[m][1], 0,0,0);
            }
        }
        f4v racc[2][2];
        #pragma unroll
        for (int m = 0; m < 2; ++m)
            #pragma unroll
            for (int nt = 0; nt < 2; ++nt)
                racc[m][nt] = (f4v){0.f,0.f,0.f,0.f};
        const short* xp = X2b + ((size_t)n*BT + b*Tv)*64;
        #pragma unroll
        for (int m = 0; m < 2; ++m){
            const short* xrp = xp + (m*16 + laneo)*64 + quad*8;
            s8v a0 = *(const s8v*)xrp;
            s8v a1 = *(const s8v*)(xrp + 32);
            racc[m][0] = __builtin_amdgcn_mfma_f32_16x16x32_bf16(a0, bwr[0][0], racc[m][0], 0,0,0);
            racc[m][0] = __builtin_amdgcn_mfma_f32_16x16x32_bf16(a1, bwr[0][1], racc[m][0], 0,0,0);
            racc[m][1] = __builtin_amdgcn_mfma_f32_16x16x32_bf16(a0, bwr[1][0], racc[m][1], 0,0,0);
            racc[m][1] = __builtin_amdgcn_mfma_f32_16x16x32_bf16(a1, bwr[1][1], racc[m][1], 0,0,0);
        }
        size_t obase = ((size_t)b*Tv*Nv + n)*Hv;
        float yv[2][2][4];
        float srow[2][4], ssrow[2][4];
        #pragma unroll
        for (int m = 0; m < 2; ++m)
            #pragma unroll
            for (int r = 0; r < 4; ++r){ srow[m][r] = 0.f; ssrow[m][r] = 0.f; }
        #pragma unroll
        for (int m = 0; m < 2; ++m){
            #pragma unroll
            for (int nt = 0; nt < 2; ++nt){
                #pragma unroll
                for (int r = 0; r < 4; ++r){
                    float gv = gelu_exact(acc[m][nt][r] + bbv[nt]);
                    float y = gv + racc[m][nt][r] + brv[nt];
                    yv[m][nt][r] = y;
                    srow[m][r] += y; ssrow[m][r] += y*y;
                }
            }
        }
        #pragma unroll
        for (int m = 0; m < 2; ++m)
            #pragma unroll
            for (int r = 0; r < 4; ++r){
                #pragma unroll
                for (int msk = 8; msk >= 1; msk >>= 1){
                    srow[m][r]  += __shfl_xor(srow[m][r],  msk, 64);
                    ssrow[m][r] += __shfl_xor(ssrow[m][r], msk, 64);
                }
            }
        if (laneo == 0){
            #pragma unroll
            for (int m = 0; m < 2; ++m)
                #pragma unroll
                for (int r = 0; r < 4; ++r){
                    int t = m*16 + quad*4 + r;
                    red[t][w][0] = srow[m][r];
                    red[t][w][1] = ssrow[m][r];
                }
        }
        __syncthreads();
        #pragma unroll
        for (int m = 0; m < 2; ++m){
            #pragma unroll
            for (int r = 0; r < 4; ++r){
                int t = m*16 + quad*4 + r;
                float s  = red[t][0][0] + red[t][1][0] + red[t][2][0] + red[t][3][0];
                float ss = red[t][0][1] + red[t][1][1] + red[t][2][1] + red[t][3][1];
                float mu = s * (1.f/128.f);
                float var = fmaxf(ss * (1.f/128.f) - mu*mu, 0.f);
                float rstd = rsqrtf(var + 1e-5f);
                #pragma unroll
                for (int nt = 0; nt < 2; ++nt){
                    int o = o_base + nt*16 + laneo;
                    out[obase + (size_t)t*Nv*Hv + o] =
                        (yv[m][nt][r] - mu)*rstd*lwv[nt] + lbv[nt];
                }
            }
        }
        __syncthreads();
    }
}

extern "C" void kernel_launch(void* const* d_in, const int* in_sizes, int n_in,
                              void* d_out, int out_size, void* d_ws, size_t ws_size,
                              hipStream_t stream){
    const float* x   = (const float*)d_in[0];
    const int*   ei  = (const int*)d_in[1];
    const float* ew  = (const float*)d_in[2];
    const float* Wg  = (const float*)d_in[3];
    const float* bg  = (const float*)d_in[4];
    const float* Wtm = (const float*)d_in[5];
    const float* btm = (const float*)d_in[6];
    const float* lw  = (const float*)d_in[7];
    const float* lb  = (const float*)d_in[8];
    const float* Wr  = (const float*)d_in[9];
    const float* br  = (const float*)d_in[10];
    float* out = (float*)d_out;

    char* ws = (char*)d_ws;
    short* Ab   = (short*)(ws + 0);            // 512 KB (512x512 bf16)
    short* W2   = (short*)(ws + 524288);       // 98304 B
    short* Wgt  = (short*)(ws + 622592);       // 16384 B
    short* Wrt  = (short*)(ws + 638976);       // 16384 B
    short* X2b  = (short*)(ws + 655360);       // 16.384 MB (n, bt*64+c)
    short* XT   = (short*)(ws + 17039360);     // 16.777 MB (bt*64+c, n-pad512)
    short* AGG2 = (short*)(ws + 33816576);     // 16.384 MB (n, bt*64+c)

    // grid: 2048 transpose + 32 A-builders + 256 weight blocks = 2336
    k_prep<<<2336, 256, 0, stream>>>(x, XT, X2b, Ab, Wtm, Wg, Wr,
                                     W2, Wgt, Wrt, ei, ew);
    k_gemm<<<512, 256, 0, stream>>>(Ab, XT, AGG2);
    k_mega<<<(Bv*Nv)/4, 256, 0, stream>>>(AGG2, X2b, W2, Wgt, Wrt,
                                          bg, btm, br, lw, lb, out);
}

// Round 11
// 253.878 us; speedup vs baseline: 1.0165x; 1.0165x over previous
//
#include <hip/hip_runtime.h>
#include <hip/hip_bf16.h>
#include <math.h>

#define Bv 8
#define Tv 32
#define Nv 500
#define NP 512           /* padded node dim for the AGG GEMM */
#define Fin 64
#define Hv 128
#define Ev 8000
#define Kv 3
#define BT (Bv*Tv)       /* 256 */
#define NCOL (BT*Fin)    /* 16384: X2b/AGG2 row length */
#define TP (Tv+2)        /* 34 LDS time rows (1 pad each side) */
#define KK (Kv*Hv)       /* 384 */
#define LDSROW 144       /* 288B row stride */

typedef __attribute__((ext_vector_type(8))) short s8v;   // 8 bf16
typedef __attribute__((ext_vector_type(4))) float f4v;   // MFMA acc

// branch-free erf (A&S 7.1.26, |err| <= 1.5e-7)
__device__ __forceinline__ float gelu_exact(float v){
    float t  = v*0.70710678118654752440f;
    float ax = fabsf(t);
    float k  = __builtin_amdgcn_rcpf(fmaf(0.3275911f, ax, 1.0f));
    float p  = k*fmaf(k, fmaf(k, fmaf(k, fmaf(k, 1.061405429f, -1.453152027f),
                                      1.421413741f), -0.284496736f), 0.254829592f);
    float e  = __expf(-ax*ax);
    float er = fmaf(-p, e, 1.0f);
    er = copysignf(er, t);
    return 0.5f*v*(1.0f + er);
}
__device__ __forceinline__ short f2bs(float f){
    union { __hip_bfloat16 h; short s; } u;
    u.h = __float2bfloat16(f);
    return u.s;
}

// ---- k_prep (ONE kernel, 2336 blocks; verified R10):
//  [0,2047]    LDS-tiled transpose x(bt,n,c) -> XT(bt*64+c, n-pad512) bf16
//              AND X2b(n, bt*64+c) bf16 (straight from pre-transpose regs)
//  [2048,2079] A-builder: block i owns A rows [i*16, i*16+16). Scans the
//              96KB L2-hot edge list twice (deg -> dinv; then own-row
//              accumulate into zeroed LDS fp32 rows + self-loop diag),
//              writes bf16 rows of Ab directly.
//  [2080,2335] weight repacks.
__global__ __launch_bounds__(256) void k_prep(const float* __restrict__ x,
        short* __restrict__ XT, short* __restrict__ X2b, short* __restrict__ Ab,
        const float* __restrict__ W, const float* __restrict__ Wg,
        const float* __restrict__ Wr,
        short* __restrict__ W2, short* __restrict__ Wgt, short* __restrict__ Wrt,
        const int* __restrict__ ei, const float* __restrict__ ew){
    int bid = blockIdx.x;
    int tid = threadIdx.x;
    if (bid < 2048){
        // one 64(n) x 64(c) tile of batch-row bt
        __shared__ short t[64][72];          // +8 pad
        int bt = bid >> 3;
        int n0 = (bid & 7) * 64;
        int r   = tid >> 2;                  // tile n-row 0..63
        int c16 = (tid & 3) * 16;            // c chunk base
        int n = n0 + r;
        short sv[16];
        if (n < Nv){
            const float4* src = (const float4*)(x + ((size_t)bt*Nv + n)*64 + c16);
            #pragma unroll
            for (int j = 0; j < 4; ++j){
                float4 v = src[j];
                sv[j*4+0]=f2bs(v.x); sv[j*4+1]=f2bs(v.y);
                sv[j*4+2]=f2bs(v.z); sv[j*4+3]=f2bs(v.w);
            }
            short* xb = X2b + (size_t)n*NCOL + bt*64 + c16;
            *(s8v*)xb       = *(s8v*)&sv[0];
            *(s8v*)(xb + 8) = *(s8v*)&sv[8];
        } else {
            #pragma unroll
            for (int j = 0; j < 16; ++j) sv[j] = 0;
        }
        #pragma unroll
        for (int j = 0; j < 16; ++j) t[r][c16+j] = sv[j];
        __syncthreads();
        int cc  = tid >> 2;                  // c 0..63
        int nn0 = (tid & 3) * 16;
        short ov[16];
        #pragma unroll
        for (int j = 0; j < 16; ++j) ov[j] = t[nn0+j][cc];
        short* dst = XT + (size_t)(bt*64 + cc)*NP + n0 + nn0;
        *(s8v*)dst       = *(s8v*)&ov[0];
        *(s8v*)(dst + 8) = *(s8v*)&ov[8];
    } else if (bid < 2080){
        // ---- A-builder for rows [r0, r0+16) ----
        __shared__ float deg[Nv];            // becomes dinv in place
        __shared__ float rowbuf[16*NP];      // 32KB, zero-init = A's zeros
        int r0 = (bid - 2048)*16;
        for (int i = tid; i < Nv; i += 256) deg[i] = 1.0f;   // self-loop weight
        for (int i = tid; i < 16*NP; i += 256) rowbuf[i] = 0.f;
        __syncthreads();
        for (int e = tid; e < Ev; e += 256)
            atomicAdd(&deg[ei[Ev + e]], ew[e]);
        __syncthreads();
        for (int i = tid; i < Nv; i += 256){
            float d = deg[i];
            deg[i] = (d > 0.f) ? rsqrtf(d) : 0.f;            // now dinv
        }
        __syncthreads();
        for (int e = tid; e < Ev; e += 256){
            int d = ei[Ev + e];
            unsigned g = (unsigned)(d - r0);
            if (g < 16u){
                int s = ei[e];
                atomicAdd(&rowbuf[g*NP + s], deg[s]*ew[e]*deg[d]);
            }
        }
        __syncthreads();
        if (tid < 16){                       // self-loop diagonal
            int row = r0 + tid;
            if (row < Nv){
                float dv = deg[row];
                rowbuf[tid*NP + row] += dv*dv;
            }
        }
        __syncthreads();
        for (int i = tid; i < 16*NP/8; i += 256){            // 1024 s8v groups
            const float* rp = &rowbuf[i*8];
            s8v o;
            #pragma unroll
            for (int j = 0; j < 8; ++j) o[j] = f2bs(rp[j]);
            *(s8v*)(Ab + (size_t)r0*NP + i*8) = o;
        }
    } else {
        int idx = (bid - 2080)*256 + tid;
        if (idx < Hv*Hv*Kv){
            int o = idx/(Hv*Kv);
            int rem = idx - o*(Hv*Kv);
            int i = rem/Kv, k = rem - i*Kv;
            W2[o*KK + k*Hv + i] = f2bs(W[idx]);
        } else if (idx < Hv*Hv*Kv + Hv*64){
            int j = idx - Hv*Hv*Kv;
            int o = j >> 6, k = j & 63;
            Wgt[j] = f2bs(Wg[k*Hv + o]);
        } else if (idx < Hv*Hv*Kv + 2*Hv*64){
            int j = idx - Hv*Hv*Kv - Hv*64;
            int o = j >> 6, k = j & 63;
            Wrt[j] = f2bs(Wr[k*Hv + o]);
        }
    }
}

// ---- k_gemm: AGG2[n][col] = sum_k Ab[n][k] * XT[col][k]
//      M=512, N=16384, K=512. Retiled 128x64 -> grid 1024 (was 512: at its
//      natural 4+ blocks/CU that was <1 residency round; 1024 gives >=2).
//      Same per-output accumulation order (k ascending) -> bit-identical. ----
__global__ __launch_bounds__(256) void k_gemm(const short* __restrict__ Ab,
        const short* __restrict__ XT, short* __restrict__ AGG2){
    int tid  = threadIdx.x;
    int w    = tid >> 6;
    int lane = tid & 63;
    int quad = lane >> 4;
    int laneo = lane & 15;
    int bid = blockIdx.x;
    int jt = bid & 255, it = bid >> 8;
    int i0 = it*128;
    int j0 = jt*64 + w*16;

    f4v acc[8];
    #pragma unroll
    for (int m = 0; m < 8; ++m)
        acc[m] = (f4v){0.f,0.f,0.f,0.f};
    #pragma unroll 2
    for (int ks = 0; ks < 16; ++ks){
        int k0 = ks*32 + quad*8;
        s8v bfr = *(const s8v*)(XT + (size_t)(j0 + laneo)*NP + k0);
        #pragma unroll
        for (int m = 0; m < 8; ++m){
            s8v afr = *(const s8v*)(Ab + (size_t)(i0 + m*16 + laneo)*NP + k0);
            acc[m] = __builtin_amdgcn_mfma_f32_16x16x32_bf16(afr, bfr, acc[m], 0,0,0);
        }
    }
    #pragma unroll
    for (int m = 0; m < 8; ++m){
        #pragma unroll
        for (int r = 0; r < 4; ++r){
            int row = i0 + m*16 + quad*4 + r;
            if (row < Nv)
                AGG2[(size_t)row*NCOL + j0 + laneo] = f2bs(acc[m][r]);
        }
    }
}

// ---- mega kernel: EXACT R8 version (verified 63.7us, FETCH 16.9MB).
//      launch_bounds(256,2) - (256,3)+ spills (proved rounds 2/4/10). ----
__global__ __launch_bounds__(256, 2) void k_mega(
        const short* __restrict__ AGG2, const short* __restrict__ X2b,
        const short* __restrict__ W2, const short* __restrict__ Wgt,
        const short* __restrict__ Wrt,
        const float* __restrict__ bg, const float* __restrict__ btm,
        const float* __restrict__ br, const float* __restrict__ lw,
        const float* __restrict__ lb, float* __restrict__ out){
    __shared__ short hs[4*TP*LDSROW];      // 39168 B
    __shared__ float red[Tv][4][2];
    int tid  = threadIdx.x;
    int w    = tid >> 6;
    int lane = tid & 63;
    int quad = lane >> 4;
    int laneo = lane & 15;
    int bid = blockIdx.x;
    int b  = bid / 125;
    int n0 = (bid - b*125) * 4;
    int o_base = w*32;

    float bgv[2], bbv[2], brv[2], lwv[2], lbv[2];
    #pragma unroll
    for (int nt = 0; nt < 2; ++nt){
        int o = o_base + nt*16 + laneo;
        bgv[nt] = bg[o]; bbv[nt] = btm[o]; brv[nt] = br[o];
        lwv[nt] = lw[o]; lbv[nt] = lb[o];
    }

    s8v bwg[2][2];
    #pragma unroll
    for (int nt = 0; nt < 2; ++nt){
        const short* wp = Wgt + (o_base + nt*16 + laneo)*64 + quad*8;
        bwg[nt][0] = *(const s8v*)wp;
        bwg[nt][1] = *(const s8v*)(wp + 32);
    }

    if (tid < 128){
        int node = tid >> 5, rem = tid & 31;
        int tp = (rem >> 4)*(TP-1), c8 = rem & 15;
        s8v z = {0,0,0,0,0,0,0,0};
        *(s8v*)&hs[node*(TP*LDSROW) + tp*LDSROW + c8*8] = z;
    }

    for (int g = 0; g < 4; ++g){
        int n = n0 + g;
        const short* ap = AGG2 + ((size_t)n*BT + b*Tv)*64;
        #pragma unroll
        for (int m = 0; m < 2; ++m){
            const short* arp = ap + (m*16 + laneo)*64 + quad*8;
            s8v a0 = *(const s8v*)arp;
            s8v a1 = *(const s8v*)(arp + 32);
            f4v h0 = {0.f,0.f,0.f,0.f}, h1 = {0.f,0.f,0.f,0.f};
            h0 = __builtin_amdgcn_mfma_f32_16x16x32_bf16(a0, bwg[0][0], h0, 0,0,0);
            h0 = __builtin_amdgcn_mfma_f32_16x16x32_bf16(a1, bwg[0][1], h0, 0,0,0);
            h1 = __builtin_amdgcn_mfma_f32_16x16x32_bf16(a0, bwg[1][0], h1, 0,0,0);
            h1 = __builtin_amdgcn_mfma_f32_16x16x32_bf16(a1, bwg[1][1], h1, 0,0,0);
            #pragma unroll
            for (int r = 0; r < 4; ++r){
                int tp = m*16 + quad*4 + r + 1;
                short* hrow = &hs[g*(TP*LDSROW) + tp*LDSROW];
                hrow[o_base + laneo]      = f2bs(gelu_exact(h0[r] + bgv[0]));
                hrow[o_base + 16 + laneo] = f2bs(gelu_exact(h1[r] + bgv[1]));
            }
        }
    }

    s8v breg[2][12], bwr[2][2];
    #pragma unroll
    for (int nt = 0; nt < 2; ++nt){
        int o = o_base + nt*16 + laneo;
        const short* wp = W2 + o*KK + quad*8;
        #pragma unroll
        for (int s = 0; s < 12; ++s)
            breg[nt][s] = *(const s8v*)(wp + s*32);
        const short* wr = Wrt + o*64 + quad*8;
        bwr[nt][0] = *(const s8v*)wr;
        bwr[nt][1] = *(const s8v*)(wr + 32);
    }
    __syncthreads();

    for (int g = 0; g < 4; ++g){
        int n = n0 + g;
        f4v acc[2][2];
        #pragma unroll
        for (int m = 0; m < 2; ++m)
            #pragma unroll
            for (int nt = 0; nt < 2; ++nt)
                acc[m][nt] = (f4v){0.f,0.f,0.f,0.f};
        #pragma unroll
        for (int m = 0; m < 2; ++m){
            #pragma unroll
            for (int s = 0; s < 12; ++s){
                int k  = s >> 2;
                int i0 = (s & 3) * 32;
                int tp = m*16 + laneo + k;
                s8v a = *(const s8v*)&hs[g*(TP*LDSROW) + tp*LDSROW + i0 + quad*8];
                acc[m][0] = __builtin_amdgcn_mfma_f32_16x16x32_bf16(a, breg[0][s], acc[m][0], 0,0,0);
                acc[m][1] = __builtin_amdgcn_mfma_f32_16x16x32_bf16(a, breg[1][s], acc[m][1], 0,0,0);
            }
        }
        f4v racc[2][2];
        #pragma unroll
        for (int m = 0; m < 2; ++m)
            #pragma unroll
            for (int nt = 0; nt < 2; ++nt)
                racc[m][nt] = (f4v){0.f,0.f,0.f,0.f};
        const short* xp = X2b + ((size_t)n*BT + b*Tv)*64;
        #pragma unroll
        for (int m = 0; m < 2; ++m){
            const short* xrp = xp + (m*16 + laneo)*64 + quad*8;
            s8v a0 = *(const s8v*)xrp;
            s8v a1 = *(const s8v*)(xrp + 32);
            racc[m][0] = __builtin_amdgcn_mfma_f32_16x16x32_bf16(a0, bwr[0][0], racc[m][0], 0,0,0);
            racc[m][0] = __builtin_amdgcn_mfma_f32_16x16x32_bf16(a1, bwr[0][1], racc[m][0], 0,0,0);
            racc[m][1] = __builtin_amdgcn_mfma_f32_16x16x32_bf16(a0, bwr[1][0], racc[m][1], 0,0,0);
            racc[m][1] = __builtin_amdgcn_mfma_f32_16x16x32_bf16(a1, bwr[1][1], racc[m][1], 0,0,0);
        }
        size_t obase = ((size_t)b*Tv*Nv + n)*Hv;
        float yv[2][2][4];
        float srow[2][4], ssrow[2][4];
        #pragma unroll
        for (int m = 0; m < 2; ++m)
            #pragma unroll
            for (int r = 0; r < 4; ++r){ srow[m][r] = 0.f; ssrow[m][r] = 0.f; }
        #pragma unroll
        for (int m = 0; m < 2; ++m){
            #pragma unroll
            for (int nt = 0; nt < 2; ++nt){
                #pragma unroll
                for (int r = 0; r < 4; ++r){
                    float gv = gelu_exact(acc[m][nt][r] + bbv[nt]);
                    float y = gv + racc[m][nt][r] + brv[nt];
                    yv[m][nt][r] = y;
                    srow[m][r] += y; ssrow[m][r] += y*y;
                }
            }
        }
        #pragma unroll
        for (int m = 0; m < 2; ++m)
            #pragma unroll
            for (int r = 0; r < 4; ++r){
                #pragma unroll
                for (int msk = 8; msk >= 1; msk >>= 1){
                    srow[m][r]  += __shfl_xor(srow[m][r],  msk, 64);
                    ssrow[m][r] += __shfl_xor(ssrow[m][r], msk, 64);
                }
            }
        if (laneo == 0){
            #pragma unroll
            for (int m = 0; m < 2; ++m)
                #pragma unroll
                for (int r = 0; r < 4; ++r){
                    int t = m*16 + quad*4 + r;
                    red[t][w][0] = srow[m][r];
                    red[t][w][1] = ssrow[m][r];
                }
        }
        __syncthreads();
        #pragma unroll
        for (int m = 0; m < 2; ++m){
            #pragma unroll
            for (int r = 0; r < 4; ++r){
                int t = m*16 + quad*4 + r;
                float s  = red[t][0][0] + red[t][1][0] + red[t][2][0] + red[t][3][0];
                float ss = red[t][0][1] + red[t][1][1] + red[t][2][1] + red[t][3][1];
                float mu = s * (1.f/128.f);
                float var = fmaxf(ss * (1.f/128.f) - mu*mu, 0.f);
                float rstd = rsqrtf(var + 1e-5f);
                #pragma unroll
                for (int nt = 0; nt < 2; ++nt){
                    int o = o_base + nt*16 + laneo;
                    out[obase + (size_t)t*Nv*Hv + o] =
                        (yv[m][nt][r] - mu)*rstd*lwv[nt] + lbv[nt];
                }
            }
        }
        __syncthreads();
    }
}

extern "C" void kernel_launch(void* const* d_in, const int* in_sizes, int n_in,
                              void* d_out, int out_size, void* d_ws, size_t ws_size,
                              hipStream_t stream){
    const float* x   = (const float*)d_in[0];
    const int*   ei  = (const int*)d_in[1];
    const float* ew  = (const float*)d_in[2];
    const float* Wg  = (const float*)d_in[3];
    const float* bg  = (const float*)d_in[4];
    const float* Wtm = (const float*)d_in[5];
    const float* btm = (const float*)d_in[6];
    const float* lw  = (const float*)d_in[7];
    const float* lb  = (const float*)d_in[8];
    const float* Wr  = (const float*)d_in[9];
    const float* br  = (const float*)d_in[10];
    float* out = (float*)d_out;

    char* ws = (char*)d_ws;
    short* Ab   = (short*)(ws + 0);            // 512 KB (512x512 bf16)
    short* W2   = (short*)(ws + 524288);       // 98304 B
    short* Wgt  = (short*)(ws + 622592);       // 16384 B
    short* Wrt  = (short*)(ws + 638976);       // 16384 B
    short* X2b  = (short*)(ws + 655360);       // 16.384 MB (n, bt*64+c)
    short* XT   = (short*)(ws + 17039360);     // 16.777 MB (bt*64+c, n-pad512)
    short* AGG2 = (short*)(ws + 33816576);     // 16.384 MB (n, bt*64+c)

    // grid: 2048 transpose + 32 A-builders + 256 weight blocks = 2336
    k_prep<<<2336, 256, 0, stream>>>(x, XT, X2b, Ab, Wtm, Wg, Wr,
                                     W2, Wgt, Wrt, ei, ew);
    k_gemm<<<1024, 256, 0, stream>>>(Ab, XT, AGG2);
    k_mega<<<(Bv*Nv)/4, 256, 0, stream>>>(AGG2, X2b, W2, Wgt, Wrt,
                                          bg, btm, br, lw, lb, out);
}

// Round 12
// 227.134 us; speedup vs baseline: 1.1362x; 1.1177x over previous
//
#include <hip/hip_runtime.h>
#include <hip/hip_bf16.h>
#include <math.h>

#define Bv 8
#define Tv 32
#define Nv 500
#define NP 512           /* padded node dim for the AGG GEMM */
#define Fin 64
#define Hv 128
#define Ev 8000
#define Kv 3
#define BT (Bv*Tv)       /* 256 */
#define NCOL (BT*Fin)    /* 16384: X2b/AGG2 row length */
#define TP (Tv+2)        /* 34 LDS time rows (1 pad each side) */
#define KK (Kv*Hv)       /* 384 */
#define LDSROW 144       /* 288B row stride */

typedef __attribute__((ext_vector_type(8))) short s8v;   // 8 bf16
typedef __attribute__((ext_vector_type(4))) float f4v;   // MFMA acc

// branch-free erf (A&S 7.1.26, |err| <= 1.5e-7)
__device__ __forceinline__ float gelu_exact(float v){
    float t  = v*0.70710678118654752440f;
    float ax = fabsf(t);
    float k  = __builtin_amdgcn_rcpf(fmaf(0.3275911f, ax, 1.0f));
    float p  = k*fmaf(k, fmaf(k, fmaf(k, fmaf(k, 1.061405429f, -1.453152027f),
                                      1.421413741f), -0.284496736f), 0.254829592f);
    float e  = __expf(-ax*ax);
    float er = fmaf(-p, e, 1.0f);
    er = copysignf(er, t);
    return 0.5f*v*(1.0f + er);
}
__device__ __forceinline__ short f2bs(float f){
    union { __hip_bfloat16 h; short s; } u;
    u.h = __float2bfloat16(f);
    return u.s;
}

// ---- k_prep (ONE kernel, 2336 blocks; verified R10/R11):
//  [0,2047]    LDS-tiled transpose x(bt,n,c) -> XT(bt*64+c, n-pad512) bf16
//              AND X2b(n, bt*64+c) bf16 (straight from pre-transpose regs)
//  [2048,2079] A-builder: block i owns A rows [i*16, i*16+16). Scans the
//              96KB L2-hot edge list twice (deg -> dinv; then own-row
//              accumulate into zeroed LDS fp32 rows + self-loop diag),
//              writes bf16 rows of Ab directly.
//  [2080,2335] weight repacks.
__global__ __launch_bounds__(256) void k_prep(const float* __restrict__ x,
        short* __restrict__ XT, short* __restrict__ X2b, short* __restrict__ Ab,
        const float* __restrict__ W, const float* __restrict__ Wg,
        const float* __restrict__ Wr,
        short* __restrict__ W2, short* __restrict__ Wgt, short* __restrict__ Wrt,
        const int* __restrict__ ei, const float* __restrict__ ew){
    int bid = blockIdx.x;
    int tid = threadIdx.x;
    if (bid < 2048){
        // one 64(n) x 64(c) tile of batch-row bt
        __shared__ short t[64][72];          // +8 pad
        int bt = bid >> 3;
        int n0 = (bid & 7) * 64;
        int r   = tid >> 2;                  // tile n-row 0..63
        int c16 = (tid & 3) * 16;            // c chunk base
        int n = n0 + r;
        short sv[16];
        if (n < Nv){
            const float4* src = (const float4*)(x + ((size_t)bt*Nv + n)*64 + c16);
            #pragma unroll
            for (int j = 0; j < 4; ++j){
                float4 v = src[j];
                sv[j*4+0]=f2bs(v.x); sv[j*4+1]=f2bs(v.y);
                sv[j*4+2]=f2bs(v.z); sv[j*4+3]=f2bs(v.w);
            }
            short* xb = X2b + (size_t)n*NCOL + bt*64 + c16;
            *(s8v*)xb       = *(s8v*)&sv[0];
            *(s8v*)(xb + 8) = *(s8v*)&sv[8];
        } else {
            #pragma unroll
            for (int j = 0; j < 16; ++j) sv[j] = 0;
        }
        #pragma unroll
        for (int j = 0; j < 16; ++j) t[r][c16+j] = sv[j];
        __syncthreads();
        int cc  = tid >> 2;                  // c 0..63
        int nn0 = (tid & 3) * 16;
        short ov[16];
        #pragma unroll
        for (int j = 0; j < 16; ++j) ov[j] = t[nn0+j][cc];
        short* dst = XT + (size_t)(bt*64 + cc)*NP + n0 + nn0;
        *(s8v*)dst       = *(s8v*)&ov[0];
        *(s8v*)(dst + 8) = *(s8v*)&ov[8];
    } else if (bid < 2080){
        // ---- A-builder for rows [r0, r0+16) ----
        __shared__ float deg[Nv];            // becomes dinv in place
        __shared__ float rowbuf[16*NP];      // 32KB, zero-init = A's zeros
        int r0 = (bid - 2048)*16;
        for (int i = tid; i < Nv; i += 256) deg[i] = 1.0f;   // self-loop weight
        for (int i = tid; i < 16*NP; i += 256) rowbuf[i] = 0.f;
        __syncthreads();
        for (int e = tid; e < Ev; e += 256)
            atomicAdd(&deg[ei[Ev + e]], ew[e]);
        __syncthreads();
        for (int i = tid; i < Nv; i += 256){
            float d = deg[i];
            deg[i] = (d > 0.f) ? rsqrtf(d) : 0.f;            // now dinv
        }
        __syncthreads();
        for (int e = tid; e < Ev; e += 256){
            int d = ei[Ev + e];
            unsigned g = (unsigned)(d - r0);
            if (g < 16u){
                int s = ei[e];
                atomicAdd(&rowbuf[g*NP + s], deg[s]*ew[e]*deg[d]);
            }
        }
        __syncthreads();
        if (tid < 16){                       // self-loop diagonal
            int row = r0 + tid;
            if (row < Nv){
                float dv = deg[row];
                rowbuf[tid*NP + row] += dv*dv;
            }
        }
        __syncthreads();
        for (int i = tid; i < 16*NP/8; i += 256){            // 1024 s8v groups
            const float* rp = &rowbuf[i*8];
            s8v o;
            #pragma unroll
            for (int j = 0; j < 8; ++j) o[j] = f2bs(rp[j]);
            *(s8v*)(Ab + (size_t)r0*NP + i*8) = o;
        }
    } else {
        int idx = (bid - 2080)*256 + tid;
        if (idx < Hv*Hv*Kv){
            int o = idx/(Hv*Kv);
            int rem = idx - o*(Hv*Kv);
            int i = rem/Kv, k = rem - i*Kv;
            W2[o*KK + k*Hv + i] = f2bs(W[idx]);
        } else if (idx < Hv*Hv*Kv + Hv*64){
            int j = idx - Hv*Hv*Kv;
            int o = j >> 6, k = j & 63;
            Wgt[j] = f2bs(Wg[k*Hv + o]);
        } else if (idx < Hv*Hv*Kv + 2*Hv*64){
            int j = idx - Hv*Hv*Kv - Hv*64;
            int o = j >> 6, k = j & 63;
            Wrt[j] = f2bs(Wr[k*Hv + o]);
        }
    }
}

// ---- k_gemm (EXACT R8 version, verified <64us): AGG2 = Ab @ XT^T
//      M=512, N=16384, K=512. grid 512 = 4 i-tiles x 128 j-tiles;
//      wave owns 32 j-cols x 128 i-rows -> 256 MFMA/wave, 2 MFMA per A-load
//      (R11's 64-col retile halved that ratio -> latency-bound, 71us). ----
__global__ __launch_bounds__(256) void k_gemm(const short* __restrict__ Ab,
        const short* __restrict__ XT, short* __restrict__ AGG2){
    int tid  = threadIdx.x;
    int w    = tid >> 6;
    int lane = tid & 63;
    int quad = lane >> 4;
    int laneo = lane & 15;
    int bid = blockIdx.x;
    int jt = bid & 127, it = bid >> 7;
    int i0 = it*128;
    int j0 = jt*128 + w*32;

    f4v acc[8][2];
    #pragma unroll
    for (int m = 0; m < 8; ++m){
        acc[m][0] = (f4v){0.f,0.f,0.f,0.f};
        acc[m][1] = (f4v){0.f,0.f,0.f,0.f};
    }
    #pragma unroll 2
    for (int ks = 0; ks < 16; ++ks){
        int k0 = ks*32 + quad*8;
        s8v bfr[2];
        #pragma unroll
        for (int nt = 0; nt < 2; ++nt)
            bfr[nt] = *(const s8v*)(XT + (size_t)(j0 + nt*16 + laneo)*NP + k0);
        #pragma unroll
        for (int m = 0; m < 8; ++m){
            s8v afr = *(const s8v*)(Ab + (size_t)(i0 + m*16 + laneo)*NP + k0);
            acc[m][0] = __builtin_amdgcn_mfma_f32_16x16x32_bf16(afr, bfr[0], acc[m][0], 0,0,0);
            acc[m][1] = __builtin_amdgcn_mfma_f32_16x16x32_bf16(afr, bfr[1], acc[m][1], 0,0,0);
        }
    }
    #pragma unroll
    for (int m = 0; m < 8; ++m){
        #pragma unroll
        for (int r = 0; r < 4; ++r){
            int row = i0 + m*16 + quad*4 + r;
            if (row < Nv){
                #pragma unroll
                for (int nt = 0; nt < 2; ++nt)
                    AGG2[(size_t)row*NCOL + j0 + nt*16 + laneo] = f2bs(acc[m][nt][r]);
            }
        }
    }
}

// ---- mega kernel: EXACT R8 version (verified 63.7us, FETCH 16.9MB).
//      launch_bounds(256,2) LOCKED - any tighter bound spills (R2/R4/R10). ----
__global__ __launch_bounds__(256, 2) void k_mega(
        const short* __restrict__ AGG2, const short* __restrict__ X2b,
        const short* __restrict__ W2, const short* __restrict__ Wgt,
        const short* __restrict__ Wrt,
        const float* __restrict__ bg, const float* __restrict__ btm,
        const float* __restrict__ br, const float* __restrict__ lw,
        const float* __restrict__ lb, float* __restrict__ out){
    __shared__ short hs[4*TP*LDSROW];      // 39168 B
    __shared__ float red[Tv][4][2];
    int tid  = threadIdx.x;
    int w    = tid >> 6;
    int lane = tid & 63;
    int quad = lane >> 4;
    int laneo = lane & 15;
    int bid = blockIdx.x;
    int b  = bid / 125;
    int n0 = (bid - b*125) * 4;
    int o_base = w*32;

    float bgv[2], bbv[2], brv[2], lwv[2], lbv[2];
    #pragma unroll
    for (int nt = 0; nt < 2; ++nt){
        int o = o_base + nt*16 + laneo;
        bgv[nt] = bg[o]; bbv[nt] = btm[o]; brv[nt] = br[o];
        lwv[nt] = lw[o]; lbv[nt] = lb[o];
    }

    s8v bwg[2][2];
    #pragma unroll
    for (int nt = 0; nt < 2; ++nt){
        const short* wp = Wgt + (o_base + nt*16 + laneo)*64 + quad*8;
        bwg[nt][0] = *(const s8v*)wp;
        bwg[nt][1] = *(const s8v*)(wp + 32);
    }

    if (tid < 128){
        int node = tid >> 5, rem = tid & 31;
        int tp = (rem >> 4)*(TP-1), c8 = rem & 15;
        s8v z = {0,0,0,0,0,0,0,0};
        *(s8v*)&hs[node*(TP*LDSROW) + tp*LDSROW + c8*8] = z;
    }

    for (int g = 0; g < 4; ++g){
        int n = n0 + g;
        const short* ap = AGG2 + ((size_t)n*BT + b*Tv)*64;
        #pragma unroll
        for (int m = 0; m < 2; ++m){
            const short* arp = ap + (m*16 + laneo)*64 + quad*8;
            s8v a0 = *(const s8v*)arp;
            s8v a1 = *(const s8v*)(arp + 32);
            f4v h0 = {0.f,0.f,0.f,0.f}, h1 = {0.f,0.f,0.f,0.f};
            h0 = __builtin_amdgcn_mfma_f32_16x16x32_bf16(a0, bwg[0][0], h0, 0,0,0);
            h0 = __builtin_amdgcn_mfma_f32_16x16x32_bf16(a1, bwg[0][1], h0, 0,0,0);
            h1 = __builtin_amdgcn_mfma_f32_16x16x32_bf16(a0, bwg[1][0], h1, 0,0,0);
            h1 = __builtin_amdgcn_mfma_f32_16x16x32_bf16(a1, bwg[1][1], h1, 0,0,0);
            #pragma unroll
            for (int r = 0; r < 4; ++r){
                int tp = m*16 + quad*4 + r + 1;
                short* hrow = &hs[g*(TP*LDSROW) + tp*LDSROW];
                hrow[o_base + laneo]      = f2bs(gelu_exact(h0[r] + bgv[0]));
                hrow[o_base + 16 + laneo] = f2bs(gelu_exact(h1[r] + bgv[1]));
            }
        }
    }

    s8v breg[2][12], bwr[2][2];
    #pragma unroll
    for (int nt = 0; nt < 2; ++nt){
        int o = o_base + nt*16 + laneo;
        const short* wp = W2 + o*KK + quad*8;
        #pragma unroll
        for (int s = 0; s < 12; ++s)
            breg[nt][s] = *(const s8v*)(wp + s*32);
        const short* wr = Wrt + o*64 + quad*8;
        bwr[nt][0] = *(const s8v*)wr;
        bwr[nt][1] = *(const s8v*)(wr + 32);
    }
    __syncthreads();

    for (int g = 0; g < 4; ++g){
        int n = n0 + g;
        f4v acc[2][2];
        #pragma unroll
        for (int m = 0; m < 2; ++m)
            #pragma unroll
            for (int nt = 0; nt < 2; ++nt)
                acc[m][nt] = (f4v){0.f,0.f,0.f,0.f};
        #pragma unroll
        for (int m = 0; m < 2; ++m){
            #pragma unroll
            for (int s = 0; s < 12; ++s){
                int k  = s >> 2;
                int i0 = (s & 3) * 32;
                int tp = m*16 + laneo + k;
                s8v a = *(const s8v*)&hs[g*(TP*LDSROW) + tp*LDSROW + i0 + quad*8];
                acc[m][0] = __builtin_amdgcn_mfma_f32_16x16x32_bf16(a, breg[0][s], acc[m][0], 0,0,0);
                acc[m][1] = __builtin_amdgcn_mfma_f32_16x16x32_bf16(a, breg[1][s], acc[m][1], 0,0,0);
            }
        }
        f4v racc[2][2];
        #pragma unroll
        for (int m = 0; m < 2; ++m)
            #pragma unroll
            for (int nt = 0; nt < 2; ++nt)
                racc[m][nt] = (f4v){0.f,0.f,0.f,0.f};
        const short* xp = X2b + ((size_t)n*BT + b*Tv)*64;
        #pragma unroll
        for (int m = 0; m < 2; ++m){
            const short* xrp = xp + (m*16 + laneo)*64 + quad*8;
            s8v a0 = *(const s8v*)xrp;
            s8v a1 = *(const s8v*)(xrp + 32);
            racc[m][0] = __builtin_amdgcn_mfma_f32_16x16x32_bf16(a0, bwr[0][0], racc[m][0], 0,0,0);
            racc[m][0] = __builtin_amdgcn_mfma_f32_16x16x32_bf16(a1, bwr[0][1], racc[m][0], 0,0,0);
            racc[m][1] = __builtin_amdgcn_mfma_f32_16x16x32_bf16(a0, bwr[1][0], racc[m][1], 0,0,0);
            racc[m][1] = __builtin_amdgcn_mfma_f32_16x16x32_bf16(a1, bwr[1][1], racc[m][1], 0,0,0);
        }
        size_t obase = ((size_t)b*Tv*Nv + n)*Hv;
        float yv[2][2][4];
        float srow[2][4], ssrow[2][4];
        #pragma unroll
        for (int m = 0; m < 2; ++m)
            #pragma unroll
            for (int r = 0; r < 4; ++r){ srow[m][r] = 0.f; ssrow[m][r] = 0.f; }
        #pragma unroll
        for (int m = 0; m < 2; ++m){
            #pragma unroll
            for (int nt = 0; nt < 2; ++nt){
                #pragma unroll
                for (int r = 0; r < 4; ++r){
                    float gv = gelu_exact(acc[m][nt][r] + bbv[nt]);
                    float y = gv + racc[m][nt][r] + brv[nt];
                    yv[m][nt][r] = y;
                    srow[m][r] += y; ssrow[m][r] += y*y;
                }
            }
        }
        #pragma unroll
        for (int m = 0; m < 2; ++m)
            #pragma unroll
            for (int r = 0; r < 4; ++r){
                #pragma unroll
                for (int msk = 8; msk >= 1; msk >>= 1){
                    srow[m][r]  += __shfl_xor(srow[m][r],  msk, 64);
                    ssrow[m][r] += __shfl_xor(ssrow[m][r], msk, 64);
                }
            }
        if (laneo == 0){
            #pragma unroll
            for (int m = 0; m < 2; ++m)
                #pragma unroll
                for (int r = 0; r < 4; ++r){
                    int t = m*16 + quad*4 + r;
                    red[t][w][0] = srow[m][r];
                    red[t][w][1] = ssrow[m][r];
                }
        }
        __syncthreads();
        #pragma unroll
        for (int m = 0; m < 2; ++m){
            #pragma unroll
            for (int r = 0; r < 4; ++r){
                int t = m*16 + quad*4 + r;
                float s  = red[t][0][0] + red[t][1][0] + red[t][2][0] + red[t][3][0];
                float ss = red[t][0][1] + red[t][1][1] + red[t][2][1] + red[t][3][1];
                float mu = s * (1.f/128.f);
                float var = fmaxf(ss * (1.f/128.f) - mu*mu, 0.f);
                float rstd = rsqrtf(var + 1e-5f);
                #pragma unroll
                for (int nt = 0; nt < 2; ++nt){
                    int o = o_base + nt*16 + laneo;
                    out[obase + (size_t)t*Nv*Hv + o] =
                        (yv[m][nt][r] - mu)*rstd*lwv[nt] + lbv[nt];
                }
            }
        }
        __syncthreads();
    }
}

extern "C" void kernel_launch(void* const* d_in, const int* in_sizes, int n_in,
                              void* d_out, int out_size, void* d_ws, size_t ws_size,
                              hipStream_t stream){
    const float* x   = (const float*)d_in[0];
    const int*   ei  = (const int*)d_in[1];
    const float* ew  = (const float*)d_in[2];
    const float* Wg  = (const float*)d_in[3];
    const float* bg  = (const float*)d_in[4];
    const float* Wtm = (const float*)d_in[5];
    const float* btm = (const float*)d_in[6];
    const float* lw  = (const float*)d_in[7];
    const float* lb  = (const float*)d_in[8];
    const float* Wr  = (const float*)d_in[9];
    const float* br  = (const float*)d_in[10];
    float* out = (float*)d_out;

    char* ws = (char*)d_ws;
    short* Ab   = (short*)(ws + 0);            // 512 KB (512x512 bf16)
    short* W2   = (short*)(ws + 524288);       // 98304 B
    short* Wgt  = (short*)(ws + 622592);       // 16384 B
    short* Wrt  = (short*)(ws + 638976);       // 16384 B
    short* X2b  = (short*)(ws + 655360);       // 16.384 MB (n, bt*64+c)
    short* XT   = (short*)(ws + 17039360);     // 16.777 MB (bt*64+c, n-pad512)
    short* AGG2 = (short*)(ws + 33816576);     // 16.384 MB (n, bt*64+c)

    // grid: 2048 transpose + 32 A-builders + 256 weight blocks = 2336
    k_prep<<<2336, 256, 0, stream>>>(x, XT, X2b, Ab, Wtm, Wg, Wr,
                                     W2, Wgt, Wrt, ei, ew);
    k_gemm<<<512, 256, 0, stream>>>(Ab, XT, AGG2);
    k_mega<<<(Bv*Nv)/4, 256, 0, stream>>>(AGG2, X2b, W2, Wgt, Wrt,
                                          bg, btm, br, lw, lb, out);
}

// Round 13
// 200.796 us; speedup vs baseline: 1.2852x; 1.1312x over previous
//
#include <hip/hip_runtime.h>
#include <hip/hip_bf16.h>
#include <math.h>

#define Bv 8
#define Tv 32
#define Nv 500
#define NP 512           /* padded node dim for the AGG GEMM */
#define Fin 64
#define Hv 128
#define Ev 8000
#define Kv 3
#define BT (Bv*Tv)       /* 256 */
#define NCOL (BT*Fin)    /* 16384: X2b/AGG2 row length */
#define TP (Tv+2)        /* 34 LDS time rows (1 pad each side) */
#define KK (Kv*Hv)       /* 384 */
#define LDSROW 144       /* 288B row stride */
#define GROW 72          /* gemm LDS row stride (144B): writes conflict-free,
                            frag reads 2-way (free, m136) */

typedef __attribute__((ext_vector_type(8))) short s8v;   // 8 bf16
typedef __attribute__((ext_vector_type(4))) float f4v;   // MFMA acc

// branch-free erf (A&S 7.1.26, |err| <= 1.5e-7)
__device__ __forceinline__ float gelu_exact(float v){
    float t  = v*0.70710678118654752440f;
    float ax = fabsf(t);
    float k  = __builtin_amdgcn_rcpf(fmaf(0.3275911f, ax, 1.0f));
    float p  = k*fmaf(k, fmaf(k, fmaf(k, fmaf(k, 1.061405429f, -1.453152027f),
                                      1.421413741f), -0.284496736f), 0.254829592f);
    float e  = __expf(-ax*ax);
    float er = fmaf(-p, e, 1.0f);
    er = copysignf(er, t);
    return 0.5f*v*(1.0f + er);
}
__device__ __forceinline__ short f2bs(float f){
    union { __hip_bfloat16 h; short s; } u;
    u.h = __float2bfloat16(f);
    return u.s;
}

// ---- k_prep (unchanged, verified R10/R11/R12) ----
__global__ __launch_bounds__(256) void k_prep(const float* __restrict__ x,
        short* __restrict__ XT, short* __restrict__ X2b, short* __restrict__ Ab,
        const float* __restrict__ W, const float* __restrict__ Wg,
        const float* __restrict__ Wr,
        short* __restrict__ W2, short* __restrict__ Wgt, short* __restrict__ Wrt,
        const int* __restrict__ ei, const float* __restrict__ ew){
    int bid = blockIdx.x;
    int tid = threadIdx.x;
    if (bid < 2048){
        // one 64(n) x 64(c) tile of batch-row bt
        __shared__ short t[64][72];          // +8 pad
        int bt = bid >> 3;
        int n0 = (bid & 7) * 64;
        int r   = tid >> 2;                  // tile n-row 0..63
        int c16 = (tid & 3) * 16;            // c chunk base
        int n = n0 + r;
        short sv[16];
        if (n < Nv){
            const float4* src = (const float4*)(x + ((size_t)bt*Nv + n)*64 + c16);
            #pragma unroll
            for (int j = 0; j < 4; ++j){
                float4 v = src[j];
                sv[j*4+0]=f2bs(v.x); sv[j*4+1]=f2bs(v.y);
                sv[j*4+2]=f2bs(v.z); sv[j*4+3]=f2bs(v.w);
            }
            short* xb = X2b + (size_t)n*NCOL + bt*64 + c16;
            *(s8v*)xb       = *(s8v*)&sv[0];
            *(s8v*)(xb + 8) = *(s8v*)&sv[8];
        } else {
            #pragma unroll
            for (int j = 0; j < 16; ++j) sv[j] = 0;
        }
        #pragma unroll
        for (int j = 0; j < 16; ++j) t[r][c16+j] = sv[j];
        __syncthreads();
        int cc  = tid >> 2;                  // c 0..63
        int nn0 = (tid & 3) * 16;
        short ov[16];
        #pragma unroll
        for (int j = 0; j < 16; ++j) ov[j] = t[nn0+j][cc];
        short* dst = XT + (size_t)(bt*64 + cc)*NP + n0 + nn0;
        *(s8v*)dst       = *(s8v*)&ov[0];
        *(s8v*)(dst + 8) = *(s8v*)&ov[8];
    } else if (bid < 2080){
        // ---- A-builder for rows [r0, r0+16) ----
        __shared__ float deg[Nv];            // becomes dinv in place
        __shared__ float rowbuf[16*NP];      // 32KB, zero-init = A's zeros
        int r0 = (bid - 2048)*16;
        for (int i = tid; i < Nv; i += 256) deg[i] = 1.0f;   // self-loop weight
        for (int i = tid; i < 16*NP; i += 256) rowbuf[i] = 0.f;
        __syncthreads();
        for (int e = tid; e < Ev; e += 256)
            atomicAdd(&deg[ei[Ev + e]], ew[e]);
        __syncthreads();
        for (int i = tid; i < Nv; i += 256){
            float d = deg[i];
            deg[i] = (d > 0.f) ? rsqrtf(d) : 0.f;            // now dinv
        }
        __syncthreads();
        for (int e = tid; e < Ev; e += 256){
            int d = ei[Ev + e];
            unsigned g = (unsigned)(d - r0);
            if (g < 16u){
                int s = ei[e];
                atomicAdd(&rowbuf[g*NP + s], deg[s]*ew[e]*deg[d]);
            }
        }
        __syncthreads();
        if (tid < 16){                       // self-loop diagonal
            int row = r0 + tid;
            if (row < Nv){
                float dv = deg[row];
                rowbuf[tid*NP + row] += dv*dv;
            }
        }
        __syncthreads();
        for (int i = tid; i < 16*NP/8; i += 256){            // 1024 s8v groups
            const float* rp = &rowbuf[i*8];
            s8v o;
            #pragma unroll
            for (int j = 0; j < 8; ++j) o[j] = f2bs(rp[j]);
            *(s8v*)(Ab + (size_t)r0*NP + i*8) = o;
        }
    } else {
        int idx = (bid - 2080)*256 + tid;
        if (idx < Hv*Hv*Kv){
            int o = idx/(Hv*Kv);
            int rem = idx - o*(Hv*Kv);
            int i = rem/Kv, k = rem - i*Kv;
            W2[o*KK + k*Hv + i] = f2bs(W[idx]);
        } else if (idx < Hv*Hv*Kv + Hv*64){
            int j = idx - Hv*Hv*Kv;
            int o = j >> 6, k = j & 63;
            Wgt[j] = f2bs(Wg[k*Hv + o]);
        } else if (idx < Hv*Hv*Kv + 2*Hv*64){
            int j = idx - Hv*Hv*Kv - Hv*64;
            int o = j >> 6, k = j & 63;
            Wrt[j] = f2bs(Wr[k*Hv + o]);
        }
    }
}

// ---- k_gemm: LDS-staged. AGG2 = Ab @ XT^T, M=512, N=16384, K=512.
//      grid 512 = 4 i-tiles x 128 j-tiles, tile 128x128, BK=64.
//      Previous direct-from-L2 version was ~95% latency-stalled (R11 cousin:
//      MfmaUtil 4.4% @ 41% occ; this one est. 40-45us hidden). Staging via
//      regs->ds_write (no global_load_lds dest constraint, free padding):
//      per BK-step 8 coalesced 16B loads/thread, then 2x(10 ds_read_b128 +
//      16 MFMA)/wave. k ascending (ks,kk) -> bit-identical accumulation. ----
__global__ __launch_bounds__(256) void k_gemm(const short* __restrict__ Ab,
        const short* __restrict__ XT, short* __restrict__ AGG2){
    __shared__ short al[128*GROW];       // 18432 B
    __shared__ short bl[128*GROW];       // 18432 B
    int tid  = threadIdx.x;
    int w    = tid >> 6;
    int lane = tid & 63;
    int quad = lane >> 4;
    int laneo = lane & 15;
    int bid = blockIdx.x;
    int jt = bid & 127, it = bid >> 7;
    int i0 = it*128;
    int j0g = jt*128;
    int jw  = w*32;

    f4v acc[8][2];
    #pragma unroll
    for (int m = 0; m < 8; ++m){
        acc[m][0] = (f4v){0.f,0.f,0.f,0.f};
        acc[m][1] = (f4v){0.f,0.f,0.f,0.f};
    }
    #pragma unroll 1
    for (int ks = 0; ks < 8; ++ks){
        // stage A-tile and B-tile (128 rows x 64 k each): 1024 16B chunks apiece
        #pragma unroll
        for (int c4 = 0; c4 < 4; ++c4){
            int c = c4*256 + tid;
            int row = c >> 3, k8 = c & 7;
            s8v va = *(const s8v*)(Ab + (size_t)(i0 + row)*NP + ks*64 + k8*8);
            s8v vb = *(const s8v*)(XT + (size_t)(j0g + row)*NP + ks*64 + k8*8);
            *(s8v*)&al[row*GROW + k8*8] = va;
            *(s8v*)&bl[row*GROW + k8*8] = vb;
        }
        __syncthreads();
        #pragma unroll
        for (int kk = 0; kk < 2; ++kk){
            int ko = kk*32 + quad*8;
            s8v bfr[2];
            bfr[0] = *(const s8v*)&bl[(jw + laneo)*GROW + ko];
            bfr[1] = *(const s8v*)&bl[(jw + 16 + laneo)*GROW + ko];
            #pragma unroll
            for (int m = 0; m < 8; ++m){
                s8v afr = *(const s8v*)&al[(m*16 + laneo)*GROW + ko];
                acc[m][0] = __builtin_amdgcn_mfma_f32_16x16x32_bf16(afr, bfr[0], acc[m][0], 0,0,0);
                acc[m][1] = __builtin_amdgcn_mfma_f32_16x16x32_bf16(afr, bfr[1], acc[m][1], 0,0,0);
            }
        }
        __syncthreads();
    }
    #pragma unroll
    for (int m = 0; m < 8; ++m){
        #pragma unroll
        for (int r = 0; r < 4; ++r){
            int row = i0 + m*16 + quad*4 + r;
            if (row < Nv){
                #pragma unroll
                for (int nt = 0; nt < 2; ++nt)
                    AGG2[(size_t)row*NCOL + j0g + jw + nt*16 + laneo] = f2bs(acc[m][nt][r]);
            }
        }
    }
}

// ---- mega kernel: EXACT R8/R12 version (verified 63.7-72.8us band).
//      launch_bounds(256,2) LOCKED - any tighter bound spills (R2/R4/R10). ----
__global__ __launch_bounds__(256, 2) void k_mega(
        const short* __restrict__ AGG2, const short* __restrict__ X2b,
        const short* __restrict__ W2, const short* __restrict__ Wgt,
        const short* __restrict__ Wrt,
        const float* __restrict__ bg, const float* __restrict__ btm,
        const float* __restrict__ br, const float* __restrict__ lw,
        const float* __restrict__ lb, float* __restrict__ out){
    __shared__ short hs[4*TP*LDSROW];      // 39168 B
    __shared__ float red[Tv][4][2];
    int tid  = threadIdx.x;
    int w    = tid >> 6;
    int lane = tid & 63;
    int quad = lane >> 4;
    int laneo = lane & 15;
    int bid = blockIdx.x;
    int b  = bid / 125;
    int n0 = (bid - b*125) * 4;
    int o_base = w*32;

    float bgv[2], bbv[2], brv[2], lwv[2], lbv[2];
    #pragma unroll
    for (int nt = 0; nt < 2; ++nt){
        int o = o_base + nt*16 + laneo;
        bgv[nt] = bg[o]; bbv[nt] = btm[o]; brv[nt] = br[o];
        lwv[nt] = lw[o]; lbv[nt] = lb[o];
    }

    s8v bwg[2][2];
    #pragma unroll
    for (int nt = 0; nt < 2; ++nt){
        const short* wp = Wgt + (o_base + nt*16 + laneo)*64 + quad*8;
        bwg[nt][0] = *(const s8v*)wp;
        bwg[nt][1] = *(const s8v*)(wp + 32);
    }

    if (tid < 128){
        int node = tid >> 5, rem = tid & 31;
        int tp = (rem >> 4)*(TP-1), c8 = rem & 15;
        s8v z = {0,0,0,0,0,0,0,0};
        *(s8v*)&hs[node*(TP*LDSROW) + tp*LDSROW + c8*8] = z;
    }

    for (int g = 0; g < 4; ++g){
        int n = n0 + g;
        const short* ap = AGG2 + ((size_t)n*BT + b*Tv)*64;
        #pragma unroll
        for (int m = 0; m < 2; ++m){
            const short* arp = ap + (m*16 + laneo)*64 + quad*8;
            s8v a0 = *(const s8v*)arp;
            s8v a1 = *(const s8v*)(arp + 32);
            f4v h0 = {0.f,0.f,0.f,0.f}, h1 = {0.f,0.f,0.f,0.f};
            h0 = __builtin_amdgcn_mfma_f32_16x16x32_bf16(a0, bwg[0][0], h0, 0,0,0);
            h0 = __builtin_amdgcn_mfma_f32_16x16x32_bf16(a1, bwg[0][1], h0, 0,0,0);
            h1 = __builtin_amdgcn_mfma_f32_16x16x32_bf16(a0, bwg[1][0], h1, 0,0,0);
            h1 = __builtin_amdgcn_mfma_f32_16x16x32_bf16(a1, bwg[1][1], h1, 0,0,0);
            #pragma unroll
            for (int r = 0; r < 4; ++r){
                int tp = m*16 + quad*4 + r + 1;
                short* hrow = &hs[g*(TP*LDSROW) + tp*LDSROW];
                hrow[o_base + laneo]      = f2bs(gelu_exact(h0[r] + bgv[0]));
                hrow[o_base + 16 + laneo] = f2bs(gelu_exact(h1[r] + bgv[1]));
            }
        }
    }

    s8v breg[2][12], bwr[2][2];
    #pragma unroll
    for (int nt = 0; nt < 2; ++nt){
        int o = o_base + nt*16 + laneo;
        const short* wp = W2 + o*KK + quad*8;
        #pragma unroll
        for (int s = 0; s < 12; ++s)
            breg[nt][s] = *(const s8v*)(wp + s*32);
        const short* wr = Wrt + o*64 + quad*8;
        bwr[nt][0] = *(const s8v*)wr;
        bwr[nt][1] = *(const s8v*)(wr + 32);
    }
    __syncthreads();

    for (int g = 0; g < 4; ++g){
        int n = n0 + g;
        f4v acc[2][2];
        #pragma unroll
        for (int m = 0; m < 2; ++m)
            #pragma unroll
            for (int nt = 0; nt < 2; ++nt)
                acc[m][nt] = (f4v){0.f,0.f,0.f,0.f};
        #pragma unroll
        for (int m = 0; m < 2; ++m){
            #pragma unroll
            for (int s = 0; s < 12; ++s){
                int k  = s >> 2;
                int i0 = (s & 3) * 32;
                int tp = m*16 + laneo + k;
                s8v a = *(const s8v*)&hs[g*(TP*LDSROW) + tp*LDSROW + i0 + quad*8];
                acc[m][0] = __builtin_amdgcn_mfma_f32_16x16x32_bf16(a, breg[0][s], acc[m][0], 0,0,0);
                acc[m][1] = __builtin_amdgcn_mfma_f32_16x16x32_bf16(a, breg[1][s], acc[m][1], 0,0,0);
            }
        }
        f4v racc[2][2];
        #pragma unroll
        for (int m = 0; m < 2; ++m)
            #pragma unroll
            for (int nt = 0; nt < 2; ++nt)
                racc[m][nt] = (f4v){0.f,0.f,0.f,0.f};
        const short* xp = X2b + ((size_t)n*BT + b*Tv)*64;
        #pragma unroll
        for (int m = 0; m < 2; ++m){
            const short* xrp = xp + (m*16 + laneo)*64 + quad*8;
            s8v a0 = *(const s8v*)xrp;
            s8v a1 = *(const s8v*)(xrp + 32);
            racc[m][0] = __builtin_amdgcn_mfma_f32_16x16x32_bf16(a0, bwr[0][0], racc[m][0], 0,0,0);
            racc[m][0] = __builtin_amdgcn_mfma_f32_16x16x32_bf16(a1, bwr[0][1], racc[m][0], 0,0,0);
            racc[m][1] = __builtin_amdgcn_mfma_f32_16x16x32_bf16(a0, bwr[1][0], racc[m][1], 0,0,0);
            racc[m][1] = __builtin_amdgcn_mfma_f32_16x16x32_bf16(a1, bwr[1][1], racc[m][1], 0,0,0);
        }
        size_t obase = ((size_t)b*Tv*Nv + n)*Hv;
        float yv[2][2][4];
        float srow[2][4], ssrow[2][4];
        #pragma unroll
        for (int m = 0; m < 2; ++m)
            #pragma unroll
            for (int r = 0; r < 4; ++r){ srow[m][r] = 0.f; ssrow[m][r] = 0.f; }
        #pragma unroll
        for (int m = 0; m < 2; ++m){
            #pragma unroll
            for (int nt = 0; nt < 2; ++nt){
                #pragma unroll
                for (int r = 0; r < 4; ++r){
                    float gv = gelu_exact(acc[m][nt][r] + bbv[nt]);
                    float y = gv + racc[m][nt][r] + brv[nt];
                    yv[m][nt][r] = y;
                    srow[m][r] += y; ssrow[m][r] += y*y;
                }
            }
        }
        #pragma unroll
        for (int m = 0; m < 2; ++m)
            #pragma unroll
            for (int r = 0; r < 4; ++r){
                #pragma unroll
                for (int msk = 8; msk >= 1; msk >>= 1){
                    srow[m][r]  += __shfl_xor(srow[m][r],  msk, 64);
                    ssrow[m][r] += __shfl_xor(ssrow[m][r], msk, 64);
                }
            }
        if (laneo == 0){
            #pragma unroll
            for (int m = 0; m < 2; ++m)
                #pragma unroll
                for (int r = 0; r < 4; ++r){
                    int t = m*16 + quad*4 + r;
                    red[t][w][0] = srow[m][r];
                    red[t][w][1] = ssrow[m][r];
                }
        }
        __syncthreads();
        #pragma unroll
        for (int m = 0; m < 2; ++m){
            #pragma unroll
            for (int r = 0; r < 4; ++r){
                int t = m*16 + quad*4 + r;
                float s  = red[t][0][0] + red[t][1][0] + red[t][2][0] + red[t][3][0];
                float ss = red[t][0][1] + red[t][1][1] + red[t][2][1] + red[t][3][1];
                float mu = s * (1.f/128.f);
                float var = fmaxf(ss * (1.f/128.f) - mu*mu, 0.f);
                float rstd = rsqrtf(var + 1e-5f);
                #pragma unroll
                for (int nt = 0; nt < 2; ++nt){
                    int o = o_base + nt*16 + laneo;
                    out[obase + (size_t)t*Nv*Hv + o] =
                        (yv[m][nt][r] - mu)*rstd*lwv[nt] + lbv[nt];
                }
            }
        }
        __syncthreads();
    }
}

extern "C" void kernel_launch(void* const* d_in, const int* in_sizes, int n_in,
                              void* d_out, int out_size, void* d_ws, size_t ws_size,
                              hipStream_t stream){
    const float* x   = (const float*)d_in[0];
    const int*   ei  = (const int*)d_in[1];
    const float* ew  = (const float*)d_in[2];
    const float* Wg  = (const float*)d_in[3];
    const float* bg  = (const float*)d_in[4];
    const float* Wtm = (const float*)d_in[5];
    const float* btm = (const float*)d_in[6];
    const float* lw  = (const float*)d_in[7];
    const float* lb  = (const float*)d_in[8];
    const float* Wr  = (const float*)d_in[9];
    const float* br  = (const float*)d_in[10];
    float* out = (float*)d_out;

    char* ws = (char*)d_ws;
    short* Ab   = (short*)(ws + 0);            // 512 KB (512x512 bf16)
    short* W2   = (short*)(ws + 524288);       // 98304 B
    short* Wgt  = (short*)(ws + 622592);       // 16384 B
    short* Wrt  = (short*)(ws + 638976);       // 16384 B
    short* X2b  = (short*)(ws + 655360);       // 16.384 MB (n, bt*64+c)
    short* XT   = (short*)(ws + 17039360);     // 16.777 MB (bt*64+c, n-pad512)
    short* AGG2 = (short*)(ws + 33816576);     // 16.384 MB (n, bt*64+c)

    // grid: 2048 transpose + 32 A-builders + 256 weight blocks = 2336
    k_prep<<<2336, 256, 0, stream>>>(x, XT, X2b, Ab, Wtm, Wg, Wr,
                                     W2, Wgt, Wrt, ei, ew);
    k_gemm<<<512, 256, 0, stream>>>(Ab, XT, AGG2);
    k_mega<<<(Bv*Nv)/4, 256, 0, stream>>>(AGG2, X2b, W2, Wgt, Wrt,
                                          bg, btm, br, lw, lb, out);
}